// Round 3
// baseline (35486.670 us; speedup 1.0000x reference)
//
#include <hip/hip_runtime.h>
#include <hip/hip_bf16.h>

// ---------------------------------------------------------------------------
// Decoder_20435454395154  — round 6
// k3 rebuilt: ZERO inter-block communication.
//   * 2 blocks x 1024 threads (16 waves). Block bb owns batch half bb*16..+16
//     (independent recurrences). Wave w = slice sq (16 gate-dims x 4 gates);
//     16 waves cover all 256 h-dims -> full W_hh resident in ONE block's
//     register file (16 waves x 128 VGPR = 512 KB packed bf16).
//   * h(t) lives entirely in LDS (double-buffered [2][16][264]); one
//     __syncthreads per step. No ring, no tags, no MALL round trip, no spin.
//   * Allocator fix: rounds 4/5 spilled the pinned weights (VGPR_Count
//     128/112 < 160 needed) because the occupancy heuristic budgeted for
//     many small-LDS blocks/CU. A 72 KB LDS guard caps occupancy at
//     1 block/CU (16 waves = 4/EU) -> per-wave VGPR budget 512, no reason
//     to spill the ~220 live regs. Validate via VGPR_Count >= 200.
//   * inp fragment for t+1 prefetched into rotating registers (hides the
//     only remaining global-load latency in the recurrence).
// ---------------------------------------------------------------------------

typedef float  f32x4 __attribute__((ext_vector_type(4)));
typedef short  s16x8 __attribute__((ext_vector_type(8)));

__device__ __forceinline__ unsigned short f2bf(float f) {
  union { float f; unsigned u; } v; v.f = f;
  unsigned r = v.u + 0x7FFFu + ((v.u >> 16) & 1u);   // RNE
  return (unsigned short)(r >> 16);
}

#define SEQ_   3072

// ------------------------------- prologue ----------------------------------

__global__ void p0_norms(const float* __restrict__ v_ih, const float* __restrict__ g_ih,
                         const float* __restrict__ v_hh, const float* __restrict__ g_hh,
                         float* __restrict__ rsih, float* __restrict__ rshh) {
  const int w = (blockIdx.x * 256 + threadIdx.x) >> 6;
  const int lane = threadIdx.x & 63;
  if (w < 1024) {
    float v = v_ih[w * 64 + lane];
    float s = v * v;
    #pragma unroll
    for (int o = 32; o > 0; o >>= 1) s += __shfl_xor(s, o);
    if (lane == 0) rsih[w] = g_ih[w] * rsqrtf(s);
  } else {
    const int r = w - 1024;
    f32x4 v = *(const f32x4*)(v_hh + (size_t)r * 256 + lane * 4);
    float s = v[0]*v[0] + v[1]*v[1] + v[2]*v[2] + v[3]*v[3];
    #pragma unroll
    for (int o = 32; o > 0; o >>= 1) s += __shfl_xor(s, o);
    if (lane == 0) rshh[r] = g_hh[r] * rsqrtf(s);
  }
}

// pack W_hh into B-fragment order: [sq(16)][g(4)][ks(8)][lane(64)][8]
__global__ void p2_packWB(const float* __restrict__ v_hh, const float* __restrict__ rshh,
                          unsigned short* __restrict__ WBp) {
  const int o = blockIdx.x * 256 + threadIdx.x;
  const int j = o & 7, l = (o >> 3) & 63, ks = (o >> 9) & 7, g = (o >> 12) & 3, sq = o >> 14;
  const int r = g * 256 + (sq >> 1) * 32 + (sq & 1) * 16 + (l & 15);
  const int k = ks * 32 + (l >> 4) * 8 + j;
  WBp[o] = f2bf(v_hh[(size_t)r * 256 + k] * rshh[r]);
}

// pack W_ih: [sq(16)][g(4)][ks(2)][lane(64)][8]
__global__ void p3_packWI(const float* __restrict__ v_ih, const float* __restrict__ rsih,
                          unsigned short* __restrict__ WIp) {
  const int o = blockIdx.x * 256 + threadIdx.x;
  const int j = o & 7, l = (o >> 3) & 63, ks = (o >> 9) & 1, g = (o >> 10) & 3, sq = o >> 12;
  const int r = g * 256 + (sq >> 1) * 32 + (sq & 1) * 16 + (l & 15);
  const int k = ks * 32 + (l >> 4) * 8 + j;
  WIp[o] = f2bf(v_ih[(size_t)r * 64 + k] * rsih[r]);
}

__global__ void k1a_cond(const float* __restrict__ z, const float* __restrict__ theta,
                         const float* __restrict__ W_theta, const float* __restrict__ b_theta,
                         float* __restrict__ cond) {
  const int i = blockIdx.x * 256 + threadIdx.x;
  const int b = i >> 8, n = i & 255;
  cond[i] = z[i] + theta[b*2+0] * W_theta[n*2+0] + theta[b*2+1] * W_theta[n*2+1] + b_theta[n];
}

__global__ __launch_bounds__(256) void k1b_dec(const float* __restrict__ cond,
                                               const float* __restrict__ W_dec,
                                               const float* __restrict__ b_dec,
                                               float* __restrict__ x) {
  const int r = blockIdx.x * 256 + threadIdx.x;
  float acc[32];
  const float bd = b_dec[r];
  #pragma unroll
  for (int b = 0; b < 32; ++b) acc[b] = bd;
  const f32x4* wp = (const f32x4*)(W_dec + (size_t)r * 256);
  for (int k4 = 0; k4 < 64; ++k4) {
    const f32x4 w = wp[k4];
    #pragma unroll
    for (int b = 0; b < 32; ++b) {
      const float* cp = cond + b * 256 + k4 * 4;
      acc[b] += w[0]*cp[0] + w[1]*cp[1] + w[2]*cp[2] + w[3]*cp[3];
    }
  }
  #pragma unroll
  for (int b = 0; b < 32; ++b) x[(size_t)b * 65536 + r] = acc[b];
}

__global__ void k1c_gnstats(const float* __restrict__ x, const float* __restrict__ gn_w,
                            const float* __restrict__ gn_b,
                            float* __restrict__ gnA, float* __restrict__ gnB) {
  __shared__ float sS[256], sQ[256];
  const int b = blockIdx.x >> 3, g = blockIdx.x & 7;
  const float* xp = x + (size_t)b * 65536 + g * 8192;
  float s = 0.f, qq = 0.f;
  for (int i = threadIdx.x; i < 8192; i += 256) { float v = xp[i]; s += v; qq += v * v; }
  sS[threadIdx.x] = s; sQ[threadIdx.x] = qq; __syncthreads();
  for (int o = 128; o > 0; o >>= 1) {
    if (threadIdx.x < o) { sS[threadIdx.x] += sS[threadIdx.x+o]; sQ[threadIdx.x] += sQ[threadIdx.x+o]; }
    __syncthreads();
  }
  if (threadIdx.x < 8) {
    const float mu  = sS[0] * (1.f / 8192.f);
    const float var = sQ[0] * (1.f / 8192.f) - mu * mu;
    const float rstd = rsqrtf(var + 1e-5f);
    const int c = g * 8 + threadIdx.x;
    const float a = gn_w[c] * rstd;
    gnA[b*64+c] = a; gnB[b*64+c] = gn_b[c] - mu * a;
  }
}

__global__ void k1d_inp(const float* __restrict__ x, const float* __restrict__ gnA,
                        const float* __restrict__ gnB, const float* __restrict__ emb,
                        const int* __restrict__ xt, unsigned short* __restrict__ inp) {
  __shared__ float xT[128 * 65];
  const int b = blockIdx.x >> 3, pt = blockIdx.x & 7, p0 = pt * 128;
  const int tid = threadIdx.x;
  for (int i = tid; i < 8192; i += 256) {
    const int p = i & 127, ch = i >> 7;
    float v = x[(size_t)b * 65536 + ch * 1024 + p0 + p];
    xT[p * 65 + ch] = v * gnA[b*64+ch] + gnB[b*64+ch];
  }
  __syncthreads();
  const int wave = tid >> 6, lane = tid & 63;
  for (int row = wave; row < 384; row += 4) {
    const int c3 = row / 128, p = row % 128;
    const int t = c3 * 1024 + p0 + p;
    float v = xT[p * 65 + lane];
    if (t > 0) {
      const int tok = xt[b * SEQ_ + t - 1];
      v += emb[tok * 64 + lane];
    }
    inp[((size_t)b * SEQ_ + t) * 64 + lane] = f2bf(v);
  }
}

// ------------------------------- recurrence --------------------------------
// 2 blocks x 1024 threads. Block bb = batch half; wave w = slice sq = w.
// Full W_hh in the block's VGPRs; full h in double-buffered LDS.
__global__ __launch_bounds__(1024, 4) void k3_lstm(
    const unsigned short* __restrict__ WBp, const unsigned short* __restrict__ WIp,
    const unsigned short* __restrict__ inp, const float* __restrict__ b_ih,
    const float* __restrict__ b_hh, unsigned short* __restrict__ hs) {
  const int bb = blockIdx.x;                  // batch half (independent)
  const int tid = threadIdx.x;
  const int w = tid >> 6, lane = tid & 63;
  const int col = lane & 15, quad = lane >> 4;
  const int sq = w;                           // 16-dim slice 0..15
  const int batch0 = bb * 16;

  __shared__ unsigned short hbuf[2][16][264]; // [parity][batch%16][dim(+8 pad)]
  __shared__ char occ_guard[72 * 1024];       // caps occupancy at 1 block/CU so
                                              // the VGPR budget is 512/wave
  if (blockIdx.x > 1000000) occ_guard[tid] = 1;  // never true, defeats DCE

  // ---- resident weight fragments (pinned; ~220 VGPR live, budget 512) ----
  s16x8 Bf[4][8];
  #pragma unroll
  for (int g = 0; g < 4; ++g)
    #pragma unroll
    for (int ks = 0; ks < 8; ++ks) {
      Bf[g][ks] = ((const s16x8*)WBp)[((sq * 4 + g) * 8 + ks) * 64 + lane];
      asm volatile("" : "+v"(Bf[g][ks]));
    }
  s16x8 WIf[4][2];
  #pragma unroll
  for (int g = 0; g < 4; ++g)
    #pragma unroll
    for (int ks = 0; ks < 2; ++ks) {
      WIf[g][ks] = ((const s16x8*)WIp)[((sq * 4 + g) * 2 + ks) * 64 + lane];
      asm volatile("" : "+v"(WIf[g][ks]));
    }
  float bias[4];
  #pragma unroll
  for (int g = 0; g < 4; ++g) {
    const int n = g * 256 + sq * 16 + col;
    bias[g] = b_ih[n] + b_hh[n];
  }

  float c[4] = {0.f, 0.f, 0.f, 0.f};
  const int mydim = sq * 16 + col;

  // input A-frag base (row = batch = batch0+col, k = quad*8 within 64)
  const unsigned short* inpRow = inp + (size_t)(batch0 + col) * SEQ_ * 64 + quad * 8;
  unsigned short* hsBase = hs + (size_t)sq * 512 + (size_t)(batch0 + quad * 4) * 16 + col;

  // rotating inp registers: a0/a1 hold step t, n0/n1 prefetch t+1
  s16x8 a0 = *(const s16x8*)(inpRow);
  s16x8 a1 = *(const s16x8*)(inpRow + 32);

  for (int t = 0; t < SEQ_; ++t) {
    const int tn = (t + 1 < SEQ_) ? (t + 1) : t;
    const s16x8 n0 = *(const s16x8*)(inpRow + (size_t)tn * 64);
    const s16x8 n1 = *(const s16x8*)(inpRow + (size_t)tn * 64 + 32);

    f32x4 acc[4];
    #pragma unroll
    for (int g = 0; g < 4; ++g) acc[g] = (f32x4){bias[g], bias[g], bias[g], bias[g]};

    // input projection
    #pragma unroll
    for (int g = 0; g < 4; ++g)
      acc[g] = __builtin_amdgcn_mfma_f32_16x16x32_bf16(a0, WIf[g][0], acc[g], 0, 0, 0);
    #pragma unroll
    for (int g = 0; g < 4; ++g)
      acc[g] = __builtin_amdgcn_mfma_f32_16x16x32_bf16(a1, WIf[g][1], acc[g], 0, 0, 0);

    // h projection from LDS (h(t-1) in hbuf[(t-1)&1])
    if (t > 0) {
      const unsigned short (*hb)[264] = hbuf[(t - 1) & 1];
      #pragma unroll
      for (int ks = 0; ks < 8; ++ks) {
        const s16x8 a = *(const s16x8*)&hb[col][ks * 32 + quad * 8];
        #pragma unroll
        for (int g = 0; g < 4; ++g)
          acc[g] = __builtin_amdgcn_mfma_f32_16x16x32_bf16(a, Bf[g][ks], acc[g], 0, 0, 0);
      }
    }

    // gates + state update + publish (4 (batch,dim) cells per lane)
    const int par = t & 1;
    #pragma unroll
    for (int r = 0; r < 4; ++r) {
      const float gi = acc[0][r], gf = acc[1][r], gg = acc[2][r], go = acc[3][r];
      const float si = 1.f / (1.f + __expf(-gi));
      const float sf = 1.f / (1.f + __expf(-gf));
      const float tg_ = 2.f / (1.f + __expf(-2.f * gg)) - 1.f;
      const float so = 1.f / (1.f + __expf(-go));
      c[r] = sf * c[r] + si * tg_;
      const float tc = 2.f / (1.f + __expf(-2.f * c[r])) - 1.f;
      const unsigned short h16 = f2bf(so * tc);
      hbuf[par][quad * 4 + r][mydim] = h16;                 // LDS h(t)
      hsBase[(size_t)t * 8192 + r * 16] = h16;              // readout buffer
    }

    __syncthreads();   // h(t) complete before any wave reads it at t+1;
                       // also orders step-t reads of hbuf[(t-1)&1] before
                       // step-(t+1) overwrites of the same buffer.
    a0 = n0; a1 = n1;
  }
}

// ------------------------------- readout -----------------------------------

// out[b,v,t] = hs[t,b,:] . W_ro[v,:] + b_ro[v]; hs in [t][slot16][b32][16] layout
__global__ __launch_bounds__(256, 1) void k4_outgemm(const unsigned short* __restrict__ ex,
                                                     const float* __restrict__ W_ro,
                                                     const float* __restrict__ b_ro,
                                                     float* __restrict__ out) {
  __shared__ unsigned short WroL[8 * 8 * 64 * 8];   // [slot=nt*8+ks][lane][8], 64KB
  const int tid = threadIdx.x, lane = tid & 63, wave = tid >> 6;
  const int bi = blockIdx.x;
  const int b = bi / 48; const int rem = bi % 48; const int tc = rem >> 1, nh = rem & 1;
  const int col = lane & 15, quad = lane >> 4;

  for (int slot = wave; slot < 64; slot += 4) {
    const int nt = slot >> 3, ks = slot & 7;
    const int v = nh * 128 + nt * 16 + col;
    const int k = ks * 32 + quad * 8;
    const float* src = W_ro + (size_t)v * 256 + k;
    s16x8 pk;
    #pragma unroll
    for (int j = 0; j < 8; ++j) pk[j] = (short)f2bf(src[j]);
    *((s16x8*)WroL + slot * 64 + lane) = pk;
  }
  __syncthreads();

  const int t0 = tc * 128 + wave * 32;
  f32x4 acc[2][8];
  #pragma unroll
  for (int mt = 0; mt < 2; ++mt)
    #pragma unroll
    for (int nt = 0; nt < 8; ++nt) acc[mt][nt] = (f32x4){0.f, 0.f, 0.f, 0.f};

  #pragma unroll
  for (int ks = 0; ks < 8; ++ks) {
    const int slot = 2 * ks + (quad >> 1), off = (quad & 1) * 8;
    const s16x8 a0 = *(const s16x8*)(ex + (((size_t)(t0 + col) * 16 + slot) * 32 + b) * 16 + off);
    const s16x8 a1 = *(const s16x8*)(ex + (((size_t)(t0 + 16 + col) * 16 + slot) * 32 + b) * 16 + off);
    #pragma unroll
    for (int nt = 0; nt < 8; ++nt) {
      const s16x8 bb = *((const s16x8*)WroL + (nt * 8 + ks) * 64 + lane);
      acc[0][nt] = __builtin_amdgcn_mfma_f32_16x16x32_bf16(a0, bb, acc[0][nt], 0, 0, 0);
      acc[1][nt] = __builtin_amdgcn_mfma_f32_16x16x32_bf16(a1, bb, acc[1][nt], 0, 0, 0);
    }
  }

  #pragma unroll
  for (int nt = 0; nt < 8; ++nt) {
    const int v = nh * 128 + nt * 16 + col;
    const float brv = b_ro[v];
    #pragma unroll
    for (int mt = 0; mt < 2; ++mt) {
      f32x4 o = acc[mt][nt];
      o[0] += brv; o[1] += brv; o[2] += brv; o[3] += brv;
      const int t = t0 + mt * 16 + quad * 4;
      *(f32x4*)(out + ((size_t)b * 256 + v) * SEQ_ + t) = o;
    }
  }
}

// ------------------------------- launcher ----------------------------------

extern "C" void kernel_launch(void* const* d_in, const int* in_sizes, int n_in,
                              void* d_out, int out_size, void* d_ws, size_t ws_size,
                              hipStream_t stream) {
  const float* z       = (const float*)d_in[0];
  const float* theta   = (const float*)d_in[1];
  const float* W_theta = (const float*)d_in[2];
  const float* b_theta = (const float*)d_in[3];
  const float* W_dec   = (const float*)d_in[4];
  const float* b_dec   = (const float*)d_in[5];
  const float* gn_w    = (const float*)d_in[6];
  const float* gn_b    = (const float*)d_in[7];
  const float* emb     = (const float*)d_in[8];
  const float* v_ih    = (const float*)d_in[9];
  const float* g_ih    = (const float*)d_in[10];
  const float* v_hh    = (const float*)d_in[11];
  const float* g_hh    = (const float*)d_in[12];
  const float* b_ih    = (const float*)d_in[13];
  const float* b_hh    = (const float*)d_in[14];
  const float* W_ro    = (const float*)d_in[15];
  const float* b_ro    = (const float*)d_in[16];
  const int*   x_tgt   = (const int*)d_in[17];
  float* out = (float*)d_out;
  char* ws = (char*)d_ws;

  // ws layout (bytes) — identical footprint to rounds 3-5 (proven to fit);
  // the former ring region is now unused.
  float*              cond  = (float*)(ws + 0);                 //    32768
  float*              x     = (float*)(ws + 32768);             //  8388608
  float*              gnA   = (float*)(ws + 8421376);           //     8192
  float*              gnB   = (float*)(ws + 8429568);           //     8192
  float*              rsih  = (float*)(ws + 8437760);           //     4096
  float*              rshh  = (float*)(ws + 8441856);           //     4096
  unsigned short*     WIp   = (unsigned short*)(ws + 8445952);  //   131072
  unsigned short*     WBp   = (unsigned short*)(ws + 8577024);  //   524288
  unsigned short*     inp   = (unsigned short*)(ws + 9101312);  // 12582912
  unsigned short*     hs    = (unsigned short*)(ws + 21684224); // 50331648  [t][slot16][b32][16]
  if (ws_size < 72409088u) return;

  p0_norms  <<<512,  256, 0, stream>>>(v_ih, g_ih, v_hh, g_hh, rsih, rshh);
  p2_packWB <<<1024, 256, 0, stream>>>(v_hh, rshh, WBp);
  p3_packWI <<<256,  256, 0, stream>>>(v_ih, rsih, WIp);
  k1a_cond  <<<32,   256, 0, stream>>>(z, theta, W_theta, b_theta, cond);
  k1b_dec   <<<256,  256, 0, stream>>>(cond, W_dec, b_dec, x);
  k1c_gnstats<<<256, 256, 0, stream>>>(x, gn_w, gn_b, gnA, gnB);
  k1d_inp   <<<256,  256, 0, stream>>>(x, gnA, gnB, emb, x_tgt, inp);
  k3_lstm   <<<2,    1024, 0, stream>>>(WBp, WIp, inp, b_ih, b_hh, hs);
  k4_outgemm<<<1536, 256, 0, stream>>>(hs, W_ro, b_ro, out);
}

// Round 4
// 7374.239 us; speedup vs baseline: 4.8122x; 4.8122x over previous
//
#include <hip/hip_runtime.h>
#include <hip/hip_bf16.h>

// ---------------------------------------------------------------------------
// Decoder_20435454395154  — round 7
// k3: 8 blocks x 256 threads = bb(2 batch halves, independent) x dq(4 dim
// quarters). One weight slice per wave (Bf[4][8]+WIf[4][2] = 160 VGPRs, the
// round-3-proven shape). Register allocator pinned via
// __attribute__((amdgpu_waves_per_eu(1,1))): budget = 512/min_waves = 512.
// Lesson from rounds 4-6: __launch_bounds__' 2nd arg is only an occupancy
// FLOOR; the allocator may target MORE waves (fewer regs) and spill — r6's
// VGPR_Count=64 at 16-wave blocks was ~180 regs of scratch churn per step.
// Exchange: quarter-partition tagged ring — publish 4 KB (2 u64/thread),
// poll 3 same-batch peers (6 u64/thread; r3 polled 7 peers x 8x redundant).
// Full h double-buffered in LDS, one __syncthreads per step.
// ---------------------------------------------------------------------------

typedef float  f32x4 __attribute__((ext_vector_type(4)));
typedef short  s16x8 __attribute__((ext_vector_type(8)));

__device__ __forceinline__ unsigned short f2bf(float f) {
  union { float f; unsigned u; } v; v.f = f;
  unsigned r = v.u + 0x7FFFu + ((v.u >> 16) & 1u);   // RNE
  return (unsigned short)(r >> 16);
}

#define SEQ_   3072

// ------------------------------- prologue ----------------------------------

__global__ void p0_norms(const float* __restrict__ v_ih, const float* __restrict__ g_ih,
                         const float* __restrict__ v_hh, const float* __restrict__ g_hh,
                         float* __restrict__ rsih, float* __restrict__ rshh) {
  const int w = (blockIdx.x * 256 + threadIdx.x) >> 6;
  const int lane = threadIdx.x & 63;
  if (w < 1024) {
    float v = v_ih[w * 64 + lane];
    float s = v * v;
    #pragma unroll
    for (int o = 32; o > 0; o >>= 1) s += __shfl_xor(s, o);
    if (lane == 0) rsih[w] = g_ih[w] * rsqrtf(s);
  } else {
    const int r = w - 1024;
    f32x4 v = *(const f32x4*)(v_hh + (size_t)r * 256 + lane * 4);
    float s = v[0]*v[0] + v[1]*v[1] + v[2]*v[2] + v[3]*v[3];
    #pragma unroll
    for (int o = 32; o > 0; o >>= 1) s += __shfl_xor(s, o);
    if (lane == 0) rshh[r] = g_hh[r] * rsqrtf(s);
  }
}

// pack W_hh into B-fragment order: [sq(16)][g(4)][ks(8)][lane(64)][8]
__global__ void p2_packWB(const float* __restrict__ v_hh, const float* __restrict__ rshh,
                          unsigned short* __restrict__ WBp) {
  const int o = blockIdx.x * 256 + threadIdx.x;
  const int j = o & 7, l = (o >> 3) & 63, ks = (o >> 9) & 7, g = (o >> 12) & 3, sq = o >> 14;
  const int r = g * 256 + (sq >> 1) * 32 + (sq & 1) * 16 + (l & 15);
  const int k = ks * 32 + (l >> 4) * 8 + j;
  WBp[o] = f2bf(v_hh[(size_t)r * 256 + k] * rshh[r]);
}

// pack W_ih: [sq(16)][g(4)][ks(2)][lane(64)][8]
__global__ void p3_packWI(const float* __restrict__ v_ih, const float* __restrict__ rsih,
                          unsigned short* __restrict__ WIp) {
  const int o = blockIdx.x * 256 + threadIdx.x;
  const int j = o & 7, l = (o >> 3) & 63, ks = (o >> 9) & 1, g = (o >> 10) & 3, sq = o >> 12;
  const int r = g * 256 + (sq >> 1) * 32 + (sq & 1) * 16 + (l & 15);
  const int k = ks * 32 + (l >> 4) * 8 + j;
  WIp[o] = f2bf(v_ih[(size_t)r * 64 + k] * rsih[r]);
}

__global__ void k1a_cond(const float* __restrict__ z, const float* __restrict__ theta,
                         const float* __restrict__ W_theta, const float* __restrict__ b_theta,
                         float* __restrict__ cond) {
  const int i = blockIdx.x * 256 + threadIdx.x;
  const int b = i >> 8, n = i & 255;
  cond[i] = z[i] + theta[b*2+0] * W_theta[n*2+0] + theta[b*2+1] * W_theta[n*2+1] + b_theta[n];
}

__global__ __launch_bounds__(256) void k1b_dec(const float* __restrict__ cond,
                                               const float* __restrict__ W_dec,
                                               const float* __restrict__ b_dec,
                                               float* __restrict__ x) {
  const int r = blockIdx.x * 256 + threadIdx.x;
  float acc[32];
  const float bd = b_dec[r];
  #pragma unroll
  for (int b = 0; b < 32; ++b) acc[b] = bd;
  const f32x4* wp = (const f32x4*)(W_dec + (size_t)r * 256);
  for (int k4 = 0; k4 < 64; ++k4) {
    const f32x4 w = wp[k4];
    #pragma unroll
    for (int b = 0; b < 32; ++b) {
      const float* cp = cond + b * 256 + k4 * 4;
      acc[b] += w[0]*cp[0] + w[1]*cp[1] + w[2]*cp[2] + w[3]*cp[3];
    }
  }
  #pragma unroll
  for (int b = 0; b < 32; ++b) x[(size_t)b * 65536 + r] = acc[b];
}

__global__ void k1c_gnstats(const float* __restrict__ x, const float* __restrict__ gn_w,
                            const float* __restrict__ gn_b,
                            float* __restrict__ gnA, float* __restrict__ gnB) {
  __shared__ float sS[256], sQ[256];
  const int b = blockIdx.x >> 3, g = blockIdx.x & 7;
  const float* xp = x + (size_t)b * 65536 + g * 8192;
  float s = 0.f, qq = 0.f;
  for (int i = threadIdx.x; i < 8192; i += 256) { float v = xp[i]; s += v; qq += v * v; }
  sS[threadIdx.x] = s; sQ[threadIdx.x] = qq; __syncthreads();
  for (int o = 128; o > 0; o >>= 1) {
    if (threadIdx.x < o) { sS[threadIdx.x] += sS[threadIdx.x+o]; sQ[threadIdx.x] += sQ[threadIdx.x+o]; }
    __syncthreads();
  }
  if (threadIdx.x < 8) {
    const float mu  = sS[0] * (1.f / 8192.f);
    const float var = sQ[0] * (1.f / 8192.f) - mu * mu;
    const float rstd = rsqrtf(var + 1e-5f);
    const int c = g * 8 + threadIdx.x;
    const float a = gn_w[c] * rstd;
    gnA[b*64+c] = a; gnB[b*64+c] = gn_b[c] - mu * a;
  }
}

__global__ void k1d_inp(const float* __restrict__ x, const float* __restrict__ gnA,
                        const float* __restrict__ gnB, const float* __restrict__ emb,
                        const int* __restrict__ xt, unsigned short* __restrict__ inp) {
  __shared__ float xT[128 * 65];
  const int b = blockIdx.x >> 3, pt = blockIdx.x & 7, p0 = pt * 128;
  const int tid = threadIdx.x;
  for (int i = tid; i < 8192; i += 256) {
    const int p = i & 127, ch = i >> 7;
    float v = x[(size_t)b * 65536 + ch * 1024 + p0 + p];
    xT[p * 65 + ch] = v * gnA[b*64+ch] + gnB[b*64+ch];
  }
  __syncthreads();
  const int wave = tid >> 6, lane = tid & 63;
  for (int row = wave; row < 384; row += 4) {
    const int c3 = row / 128, p = row % 128;
    const int t = c3 * 1024 + p0 + p;
    float v = xT[p * 65 + lane];
    if (t > 0) {
      const int tok = xt[b * SEQ_ + t - 1];
      v += emb[tok * 64 + lane];
    }
    inp[((size_t)b * SEQ_ + t) * 64 + lane] = f2bf(v);
  }
}

// ------------------------------- recurrence --------------------------------
// 8 blocks x 256 threads: bb = blockIdx&1 (batch half), dq = blockIdx>>1
// (dim quarter). Wave w owns slice sq = dq*4+w. M = 16 batches.
__global__ __launch_bounds__(256)
__attribute__((amdgpu_waves_per_eu(1, 1)))
void k3_lstm(
    const unsigned short* __restrict__ WBp, const unsigned short* __restrict__ WIp,
    const unsigned short* __restrict__ inp, const float* __restrict__ b_ih,
    const float* __restrict__ b_hh, unsigned short* __restrict__ hs,
    unsigned long long* __restrict__ ring64) {
  const int bb = blockIdx.x & 1;              // batch half
  const int dq = blockIdx.x >> 1;             // dim quarter 0..3
  const int tid = threadIdx.x;
  const int w = tid >> 6, lane = tid & 63;
  const int col = lane & 15, quad = lane >> 4;
  const int sq = dq * 4 + w;                  // global 16-dim slice 0..15
  const int batch0 = bb * 16;
  const int dloc = w * 16 + col;              // dim local to this block (0..63)
  const int mydim = sq * 16 + col;            // global dim

  __shared__ unsigned short hbuf[2][16][264]; // [parity][batch%16][dim(+8 pad)]

  // ---- resident weight fragments (~160 VGPR; budget 512 via waves_per_eu) --
  s16x8 Bf[4][8];
  #pragma unroll
  for (int g = 0; g < 4; ++g)
    #pragma unroll
    for (int ks = 0; ks < 8; ++ks) {
      Bf[g][ks] = ((const s16x8*)WBp)[((sq * 4 + g) * 8 + ks) * 64 + lane];
      asm volatile("" : "+v"(Bf[g][ks]));
    }
  s16x8 WIf[4][2];
  #pragma unroll
  for (int g = 0; g < 4; ++g)
    #pragma unroll
    for (int ks = 0; ks < 2; ++ks) {
      WIf[g][ks] = ((const s16x8*)WIp)[((sq * 4 + g) * 2 + ks) * 64 + lane];
      asm volatile("" : "+v"(WIf[g][ks]));
    }
  float bias[4];
  #pragma unroll
  for (int g = 0; g < 4; ++g) {
    const int n = g * 256 + sq * 16 + col;
    bias[g] = b_ih[n] + b_hh[n];
  }

  float c[4] = {0.f, 0.f, 0.f, 0.f};

  // input A-frag base (row = batch = batch0+col, k = quad*8 within 64)
  const unsigned short* inpRow = inp + (size_t)(batch0 + col) * SEQ_ * 64 + quad * 8;
  unsigned short* hsBase = hs + (size_t)sq * 512 + (size_t)(batch0 + quad * 4) * 16 + col;

  // ring: region (rs, bb, q) = 512 u64 = [dloc(64)][batch(16)] tagged u32.
  // writer: 2 u64 at dloc*8 + quad*2. reader: region q != dq, 2 u64 at tid*2,
  // covering peer-dim pq*64 + (tid>>2), batches (tid&3)*4 .. +4.
  const int wrOff = dloc * 8 + quad * 2;
  const int pq0 = (dq + 1) & 3, pq1 = (dq + 2) & 3, pq2 = (dq + 3) & 3;
  const int rdOff = tid * 2;
  const int prow = tid >> 2;                  // peer-local dim row 0..63
  const int pb0 = (tid & 3) * 4;              // first batch row of the 4
  const int pdim0 = pq0 * 64 + prow, pdim1 = pq1 * 64 + prow, pdim2 = pq2 * 64 + prow;

  // rotating inp prefetch
  s16x8 a0 = *(const s16x8*)(inpRow);
  s16x8 a1 = *(const s16x8*)(inpRow + 32);

  for (int t = 0; t < SEQ_; ++t) {
    const int tn = (t + 1 < SEQ_) ? (t + 1) : t;
    const s16x8 n0 = *(const s16x8*)(inpRow + (size_t)tn * 64);
    const s16x8 n1 = *(const s16x8*)(inpRow + (size_t)tn * 64 + 32);

    f32x4 acc[4];
    #pragma unroll
    for (int g = 0; g < 4; ++g) acc[g] = (f32x4){bias[g], bias[g], bias[g], bias[g]};

    // input projection (independent of h) — overlaps the poll latency
    #pragma unroll
    for (int g = 0; g < 4; ++g)
      acc[g] = __builtin_amdgcn_mfma_f32_16x16x32_bf16(a0, WIf[g][0], acc[g], 0, 0, 0);
    #pragma unroll
    for (int g = 0; g < 4; ++g)
      acc[g] = __builtin_amdgcn_mfma_f32_16x16x32_bf16(a1, WIf[g][1], acc[g], 0, 0, 0);

    if (t > 0) {
      // ---- poll 3 peer quarters of h(t-1): 6 u64 per thread ----
      const int rs = (t - 1) & 3;
      const unsigned tagIn = (0x5000u | (unsigned)(t - 1)) << 16;
      const unsigned long long* r0 = ring64 + (size_t)((rs * 2 + bb) * 4 + pq0) * 512 + rdOff;
      const unsigned long long* r1 = ring64 + (size_t)((rs * 2 + bb) * 4 + pq1) * 512 + rdOff;
      const unsigned long long* r2 = ring64 + (size_t)((rs * 2 + bb) * 4 + pq2) * 512 + rdOff;
      unsigned long long v0a, v0b, v1a, v1b, v2a, v2b;
      unsigned bad;
      do {
        v0a = __hip_atomic_load(r0 + 0, __ATOMIC_RELAXED, __HIP_MEMORY_SCOPE_SYSTEM);
        v0b = __hip_atomic_load(r0 + 1, __ATOMIC_RELAXED, __HIP_MEMORY_SCOPE_SYSTEM);
        v1a = __hip_atomic_load(r1 + 0, __ATOMIC_RELAXED, __HIP_MEMORY_SCOPE_SYSTEM);
        v1b = __hip_atomic_load(r1 + 1, __ATOMIC_RELAXED, __HIP_MEMORY_SCOPE_SYSTEM);
        v2a = __hip_atomic_load(r2 + 0, __ATOMIC_RELAXED, __HIP_MEMORY_SCOPE_SYSTEM);
        v2b = __hip_atomic_load(r2 + 1, __ATOMIC_RELAXED, __HIP_MEMORY_SCOPE_SYSTEM);
        bad  = ((unsigned)v0a ^ tagIn) | ((unsigned)(v0a >> 32) ^ tagIn);
        bad |= ((unsigned)v0b ^ tagIn) | ((unsigned)(v0b >> 32) ^ tagIn);
        bad |= ((unsigned)v1a ^ tagIn) | ((unsigned)(v1a >> 32) ^ tagIn);
        bad |= ((unsigned)v1b ^ tagIn) | ((unsigned)(v1b >> 32) ^ tagIn);
        bad |= ((unsigned)v2a ^ tagIn) | ((unsigned)(v2a >> 32) ^ tagIn);
        bad |= ((unsigned)v2b ^ tagIn) | ((unsigned)(v2b >> 32) ^ tagIn);
        bad >>= 16;
      } while (bad != 0);
      const int pr = (t - 1) & 1;
      hbuf[pr][pb0 + 0][pdim0] = (unsigned short)v0a;
      hbuf[pr][pb0 + 1][pdim0] = (unsigned short)(v0a >> 32);
      hbuf[pr][pb0 + 2][pdim0] = (unsigned short)v0b;
      hbuf[pr][pb0 + 3][pdim0] = (unsigned short)(v0b >> 32);
      hbuf[pr][pb0 + 0][pdim1] = (unsigned short)v1a;
      hbuf[pr][pb0 + 1][pdim1] = (unsigned short)(v1a >> 32);
      hbuf[pr][pb0 + 2][pdim1] = (unsigned short)v1b;
      hbuf[pr][pb0 + 3][pdim1] = (unsigned short)(v1b >> 32);
      hbuf[pr][pb0 + 0][pdim2] = (unsigned short)v2a;
      hbuf[pr][pb0 + 1][pdim2] = (unsigned short)(v2a >> 32);
      hbuf[pr][pb0 + 2][pdim2] = (unsigned short)v2b;
      hbuf[pr][pb0 + 3][pdim2] = (unsigned short)(v2b >> 32);

      __syncthreads();   // hbuf[pr] complete (own quarter written at t-1)

      // ---- h projection ----
      const unsigned short (*hb)[264] = hbuf[pr];
      #pragma unroll
      for (int ks = 0; ks < 8; ++ks) {
        const s16x8 a = *(const s16x8*)&hb[col][ks * 32 + quad * 8];
        #pragma unroll
        for (int g = 0; g < 4; ++g)
          acc[g] = __builtin_amdgcn_mfma_f32_16x16x32_bf16(a, Bf[g][ks], acc[g], 0, 0, 0);
      }
    }

    // ---- gates + state update + publish (4 (batch,dim) cells per lane) ----
    const unsigned tagOut = (0x5000u | (unsigned)t) << 16;
    const int par = t & 1;
    unsigned tga[4];
    #pragma unroll
    for (int r = 0; r < 4; ++r) {
      const float gi = acc[0][r], gf = acc[1][r], gg = acc[2][r], go = acc[3][r];
      const float si = 1.f / (1.f + __expf(-gi));
      const float sf = 1.f / (1.f + __expf(-gf));
      const float tg_ = 2.f / (1.f + __expf(-2.f * gg)) - 1.f;
      const float so = 1.f / (1.f + __expf(-go));
      c[r] = sf * c[r] + si * tg_;
      const float tc = 2.f / (1.f + __expf(-2.f * c[r])) - 1.f;
      const unsigned short h16 = f2bf(so * tc);
      hbuf[par][quad * 4 + r][mydim] = h16;                 // LDS own quarter
      tga[r] = tagOut | h16;
      hsBase[(size_t)t * 8192 + r * 16] = h16;              // readout buffer
    }
    unsigned long long* wp =
        ring64 + (size_t)(((t & 3) * 2 + bb) * 4 + dq) * 512 + wrOff;
    __hip_atomic_store(wp + 0,
                       (unsigned long long)tga[0] | ((unsigned long long)tga[1] << 32),
                       __ATOMIC_RELAXED, __HIP_MEMORY_SCOPE_SYSTEM);
    __hip_atomic_store(wp + 1,
                       (unsigned long long)tga[2] | ((unsigned long long)tga[3] << 32),
                       __ATOMIC_RELAXED, __HIP_MEMORY_SCOPE_SYSTEM);
    // ring slot reuse distance 4, peer skew <= 1 -> safe; every u32 tagged.
    a0 = n0; a1 = n1;
  }
}

// ------------------------------- readout -----------------------------------

// out[b,v,t] = hs[t,b,:] . W_ro[v,:] + b_ro[v]; hs in [t][slot16][b32][16] layout
__global__ __launch_bounds__(256, 1) void k4_outgemm(const unsigned short* __restrict__ ex,
                                                     const float* __restrict__ W_ro,
                                                     const float* __restrict__ b_ro,
                                                     float* __restrict__ out) {
  __shared__ unsigned short WroL[8 * 8 * 64 * 8];   // [slot=nt*8+ks][lane][8], 64KB
  const int tid = threadIdx.x, lane = tid & 63, wave = tid >> 6;
  const int bi = blockIdx.x;
  const int b = bi / 48; const int rem = bi % 48; const int tc = rem >> 1, nh = rem & 1;
  const int col = lane & 15, quad = lane >> 4;

  for (int slot = wave; slot < 64; slot += 4) {
    const int nt = slot >> 3, ks = slot & 7;
    const int v = nh * 128 + nt * 16 + col;
    const int k = ks * 32 + quad * 8;
    const float* src = W_ro + (size_t)v * 256 + k;
    s16x8 pk;
    #pragma unroll
    for (int j = 0; j < 8; ++j) pk[j] = (short)f2bf(src[j]);
    *((s16x8*)WroL + slot * 64 + lane) = pk;
  }
  __syncthreads();

  const int t0 = tc * 128 + wave * 32;
  f32x4 acc[2][8];
  #pragma unroll
  for (int mt = 0; mt < 2; ++mt)
    #pragma unroll
    for (int nt = 0; nt < 8; ++nt) acc[mt][nt] = (f32x4){0.f, 0.f, 0.f, 0.f};

  #pragma unroll
  for (int ks = 0; ks < 8; ++ks) {
    const int slot = 2 * ks + (quad >> 1), off = (quad & 1) * 8;
    const s16x8 a0 = *(const s16x8*)(ex + (((size_t)(t0 + col) * 16 + slot) * 32 + b) * 16 + off);
    const s16x8 a1 = *(const s16x8*)(ex + (((size_t)(t0 + 16 + col) * 16 + slot) * 32 + b) * 16 + off);
    #pragma unroll
    for (int nt = 0; nt < 8; ++nt) {
      const s16x8 bb = *((const s16x8*)WroL + (nt * 8 + ks) * 64 + lane);
      acc[0][nt] = __builtin_amdgcn_mfma_f32_16x16x32_bf16(a0, bb, acc[0][nt], 0, 0, 0);
      acc[1][nt] = __builtin_amdgcn_mfma_f32_16x16x32_bf16(a1, bb, acc[1][nt], 0, 0, 0);
    }
  }

  #pragma unroll
  for (int nt = 0; nt < 8; ++nt) {
    const int v = nh * 128 + nt * 16 + col;
    const float brv = b_ro[v];
    #pragma unroll
    for (int mt = 0; mt < 2; ++mt) {
      f32x4 o = acc[mt][nt];
      o[0] += brv; o[1] += brv; o[2] += brv; o[3] += brv;
      const int t = t0 + mt * 16 + quad * 4;
      *(f32x4*)(out + ((size_t)b * 256 + v) * SEQ_ + t) = o;
    }
  }
}

// ------------------------------- launcher ----------------------------------

extern "C" void kernel_launch(void* const* d_in, const int* in_sizes, int n_in,
                              void* d_out, int out_size, void* d_ws, size_t ws_size,
                              hipStream_t stream) {
  const float* z       = (const float*)d_in[0];
  const float* theta   = (const float*)d_in[1];
  const float* W_theta = (const float*)d_in[2];
  const float* b_theta = (const float*)d_in[3];
  const float* W_dec   = (const float*)d_in[4];
  const float* b_dec   = (const float*)d_in[5];
  const float* gn_w    = (const float*)d_in[6];
  const float* gn_b    = (const float*)d_in[7];
  const float* emb     = (const float*)d_in[8];
  const float* v_ih    = (const float*)d_in[9];
  const float* g_ih    = (const float*)d_in[10];
  const float* v_hh    = (const float*)d_in[11];
  const float* g_hh    = (const float*)d_in[12];
  const float* b_ih    = (const float*)d_in[13];
  const float* b_hh    = (const float*)d_in[14];
  const float* W_ro    = (const float*)d_in[15];
  const float* b_ro    = (const float*)d_in[16];
  const int*   x_tgt   = (const int*)d_in[17];
  float* out = (float*)d_out;
  char* ws = (char*)d_ws;

  // ws layout (bytes) — identical footprint to rounds 3-6 (proven to fit)
  float*              cond  = (float*)(ws + 0);                 //    32768
  float*              x     = (float*)(ws + 32768);             //  8388608
  float*              gnA   = (float*)(ws + 8421376);           //     8192
  float*              gnB   = (float*)(ws + 8429568);           //     8192
  float*              rsih  = (float*)(ws + 8437760);           //     4096
  float*              rshh  = (float*)(ws + 8441856);           //     4096
  unsigned short*     WIp   = (unsigned short*)(ws + 8445952);  //   131072
  unsigned short*     WBp   = (unsigned short*)(ws + 8577024);  //   524288
  unsigned short*     inp   = (unsigned short*)(ws + 9101312);  // 12582912
  unsigned short*     hs    = (unsigned short*)(ws + 21684224); // 50331648  [t][slot16][b32][16]
  unsigned long long* ring64= (unsigned long long*)(ws + 72015872); // 131072 (4rs x 2bb x 4dq x 4KB tagged)
  if (ws_size < 72409088u) return;

  p0_norms  <<<512,  256, 0, stream>>>(v_ih, g_ih, v_hh, g_hh, rsih, rshh);
  p2_packWB <<<1024, 256, 0, stream>>>(v_hh, rshh, WBp);
  p3_packWI <<<256,  256, 0, stream>>>(v_ih, rsih, WIp);
  k1a_cond  <<<32,   256, 0, stream>>>(z, theta, W_theta, b_theta, cond);
  k1b_dec   <<<256,  256, 0, stream>>>(cond, W_dec, b_dec, x);
  k1c_gnstats<<<256, 256, 0, stream>>>(x, gn_w, gn_b, gnA, gnB);
  k1d_inp   <<<256,  256, 0, stream>>>(x, gnA, gnB, emb, x_tgt, inp);
  k3_lstm   <<<8,    256, 0, stream>>>(WBp, WIp, inp, b_ih, b_hh, hs, ring64);
  k4_outgemm<<<1536, 256, 0, stream>>>(hs, W_ro, b_ro, out);
}